// Round 2
// baseline (17583.229 us; speedup 1.0000x reference)
//
#include <hip/hip_runtime.h>
#include <hip/hip_bf16.h>

// SimpleRNN: h_{s+1} = tanh(W @ [h_s; x_s] + b),  W = [W_h | W_x] (512 x 1024)
// S=2048, B=64, HID=512. Output: h_final (64,512) fp32.
//
// Persistent flag-sync design (32 wgs x 256 thr, all co-resident on 256 CUs):
//   4 batch-groups x 16 batches; each group has 8 member wgs owning 64 features.
//   Each wave owns one 16-feature MFMA tile; its W slice (K=1024, bf16) lives
//   in VGPRs for the whole kernel (128 VGPR/lane; 8 members x 4 waves = full W).
//   Per step: x-part (loads+convert+16 MFMAs) runs BEFORE the flag spin (slack);
//   critical path after flags = 32 u64 h-loads + 16 MFMAs + tanh + publish.
//   h exchanged via triple-buffered bf16 buffer in ws + per-member step flags,
//   all agent-scope atomics (cross-XCD-coherent message passing).

#define S_LEN  2048
#define BATCH  64
#define HID    512
#define KDIM   1024
#define GROUPS 4
#define MEMBERS 8
#define BSL    16          // batches per group
#define FSL    64          // features per member wg
#define THREADS 256

typedef __attribute__((ext_vector_type(8))) short short8;
typedef __attribute__((ext_vector_type(4))) float f32x4;

#define HBUF_ELEMS   (GROUPS*BSL*HID)        // 32768 bf16 per buffer
#define HBUF_U64     (HBUF_ELEMS/4)          // 8192 u64 per buffer
#define FLAG_OFF_U64 (3*HBUF_U64)            // flags after 3 buffers

__device__ __forceinline__ short8 pack_bf16x8(float4 a, float4 b) {
  union { __hip_bfloat162 h2[4]; short8 s8; } u;
  u.h2[0] = __float22bfloat162_rn(make_float2(a.x, a.y));
  u.h2[1] = __float22bfloat162_rn(make_float2(a.z, a.w));
  u.h2[2] = __float22bfloat162_rn(make_float2(b.x, b.y));
  u.h2[3] = __float22bfloat162_rn(make_float2(b.z, b.w));
  return u.s8;
}

__device__ __forceinline__ float fast_tanh(float x) {
  // tanh(x) = 1 - 2/(exp(2x)+1); exact saturation at +-inf, fine near 0
  float e = __expf(2.0f * x);
  return 1.0f - 2.0f / (e + 1.0f);
}

__global__ void __launch_bounds__(256, 1) rnn_init(unsigned long long* ws) {
  int i = blockIdx.x * blockDim.x + threadIdx.x;
  if (i < HBUF_U64) {
    ws[i] = 0ULL;                               // h0 = zeros (buffer 0)
  } else if (i < HBUF_U64 + 16) {
    ws[FLAG_OFF_U64 + (i - HBUF_U64)] = 0ULL;   // flags[4][8] (u32) = 16 u64
  }
}

__global__ void __launch_bounds__(THREADS, 1) rnn_main(
    const float* __restrict__ x,      // [S][B][512]
    const float* __restrict__ W,      // [512][1024]
    const float* __restrict__ bias,   // [512]
    float* __restrict__ out,          // [B][512]
    unsigned short* __restrict__ hbuf, // ws: [3][GROUPS][BSL][HID] bf16
    unsigned int* __restrict__ flags) {// ws+off: [GROUPS][MEMBERS]
  const int bid  = blockIdx.x;
  const int g    = bid & (GROUPS - 1);   // batch group 0..3
  const int m    = bid >> 2;             // member 0..7 (feature slice)
  const int tid  = threadIdx.x;
  const int wid  = tid >> 6;             // wave 0..3 (one 16-feat tile each)
  const int lane = tid & 63;
  const int col  = lane & 15;            // MFMA col = batch-in-group; A-row feat
  const int khi  = lane >> 4;            // 0..3: k-subgroup (8 elems each)

  // ---- W slice -> registers as bf16 A-fragments, once (128 VGPR/lane) ----
  const int feat_row = m * FSL + wid * 16 + col;      // A row (feature)
  short8 aW[32];
  {
    const float* Wp = W + (size_t)feat_row * KDIM;
#pragma unroll
    for (int kk = 0; kk < 32; ++kk) {
      int k = kk * 32 + khi * 8;
      float4 w0 = *(const float4*)(Wp + k);
      float4 w1 = *(const float4*)(Wp + k + 4);
      aW[kk] = pack_bf16x8(w0, w1);
    }
  }
  // bias for this lane's 4 C rows: feat = featw + r  (C/D: col=lane&15,
  // row=(lane>>4)*4+reg  [m89-verified layout])
  const int featw = m * FSL + wid * 16 + khi * 4;
  float bfrag[4];
#pragma unroll
  for (int r = 0; r < 4; ++r) bfrag[r] = bias[featw + r];

  const int bat = g * BSL + col;                      // global batch index
  const unsigned short* hread_base = hbuf + (size_t)bat * HID;
  unsigned short* hwrite_base = hbuf + (size_t)bat * HID + featw;

  unsigned int* gflags = flags + g * MEMBERS;
  unsigned int* myflag = gflags + m;

  int rbuf = 0;
  const float* xp0 = x + (size_t)bat * HID;           // x[0][bat][0]

  for (int s = 0; s < S_LEN; ++s) {
    int wbuf = rbuf + 1; if (wbuf == 3) wbuf = 0;

    // ================= x phase (independent of h -> off critical path) ====
    // stage x[s][bat][:] for this lane's k-subgroups
    float4 xv[32];
    const float* xps = xp0 + khi * 8;
#pragma unroll
    for (int t = 0; t < 16; ++t) {
      xv[2 * t]     = *(const float4*)(xps + t * 32);
      xv[2 * t + 1] = *(const float4*)(xps + t * 32 + 4);
    }
    // convert to bf16 B-fragments (xv dies here; 64 VGPR live across spin)
    short8 bx[16];
#pragma unroll
    for (int t = 0; t < 16; ++t) bx[t] = pack_bf16x8(xv[2 * t], xv[2 * t + 1]);
    // x-part MFMAs: k = 512..1023 (W_x columns), 2 chains, bias in chain 0
    f32x4 ax0 = {bfrag[0], bfrag[1], bfrag[2], bfrag[3]};
    f32x4 ax1 = {0.f, 0.f, 0.f, 0.f};
#pragma unroll
    for (int t = 0; t < 16; ++t) {
      f32x4& A = (t & 1) ? ax1 : ax0;
      A = __builtin_amdgcn_mfma_f32_16x16x32_bf16(aW[16 + t], bx[t], A, 0, 0, 0);
    }

    // ================= wait for h_s: all members' flags >= s ==============
    if (s > 0) {
      const unsigned int tgt = (unsigned int)s;
      while (true) {
        unsigned int fl = __hip_atomic_load(gflags + (lane & (MEMBERS - 1)),
                                            __ATOMIC_ACQUIRE, __HIP_MEMORY_SCOPE_AGENT);
        if (__all((int)(fl >= tgt))) break;
      }
    }

    // ================= h phase (critical path) ============================
    // issue all 32 u64 loads first (one latency), then 16 MFMAs over 4 chains
    unsigned long long hl[32];
    const unsigned long long* hp =
        (const unsigned long long*)(hread_base + (size_t)rbuf * HBUF_ELEMS) + khi * 2;
#pragma unroll
    for (int kk = 0; kk < 16; ++kk) {
      hl[2 * kk]     = __hip_atomic_load(hp + kk * 8,
                                         __ATOMIC_RELAXED, __HIP_MEMORY_SCOPE_AGENT);
      hl[2 * kk + 1] = __hip_atomic_load(hp + kk * 8 + 1,
                                         __ATOMIC_RELAXED, __HIP_MEMORY_SCOPE_AGENT);
    }
    f32x4 ah0 = {0.f, 0.f, 0.f, 0.f};
    f32x4 ah1 = {0.f, 0.f, 0.f, 0.f};
    f32x4 ah2 = {0.f, 0.f, 0.f, 0.f};
    f32x4 ah3 = {0.f, 0.f, 0.f, 0.f};
#pragma unroll
    for (int kk = 0; kk < 16; ++kk) {
      union { unsigned long long q[2]; short8 s8; } u;
      u.q[0] = hl[2 * kk]; u.q[1] = hl[2 * kk + 1];
      f32x4& A = (kk & 2) ? ((kk & 1) ? ah3 : ah2) : ((kk & 1) ? ah1 : ah0);
      A = __builtin_amdgcn_mfma_f32_16x16x32_bf16(aW[kk], u.s8, A, 0, 0, 0);
    }

    f32x4 pre = ((ah0 + ah1) + (ah2 + ah3)) + (ax0 + ax1);
    float h0 = fast_tanh(pre.x), h1 = fast_tanh(pre.y);
    float h2 = fast_tanh(pre.z), h3 = fast_tanh(pre.w);

    if (s == S_LEN - 1) {
      f32x4 o = {h0, h1, h2, h3};
      *(f32x4*)(out + (size_t)bat * HID + featw) = o;   // 16B-aligned (featw%4==0)
    } else {
      // publish h_{s+1}: 4 bf16 = one u64 agent-scope store, barrier, flag
      union { __hip_bfloat162 h2v[2]; unsigned long long q; } wv;
      wv.h2v[0] = __float22bfloat162_rn(make_float2(h0, h1));
      wv.h2v[1] = __float22bfloat162_rn(make_float2(h2, h3));
      __hip_atomic_store((unsigned long long*)(hwrite_base + (size_t)wbuf * HBUF_ELEMS),
                         wv.q, __ATOMIC_RELAXED, __HIP_MEMORY_SCOPE_AGENT);
      __syncthreads();   // all 4 waves drain stores (vmcnt0) before the flag
      if (tid == 0) {
        __hip_atomic_store(myflag, (unsigned int)(s + 1),
                           __ATOMIC_RELEASE, __HIP_MEMORY_SCOPE_AGENT);
      }
    }
    rbuf = wbuf;
    xp0 += BATCH * HID;
  }
}

extern "C" void kernel_launch(void* const* d_in, const int* in_sizes, int n_in,
                              void* d_out, int out_size, void* d_ws, size_t ws_size,
                              hipStream_t stream) {
  const float* x  = (const float*)d_in[0];
  const float* W  = (const float*)d_in[1];
  const float* b  = (const float*)d_in[2];
  float* out      = (float*)d_out;
  unsigned short* hbuf  = (unsigned short*)d_ws;
  unsigned int*   flags = (unsigned int*)((unsigned long long*)d_ws + FLAG_OFF_U64);

  // ws is re-poisoned 0xAA before every timed launch -> must zero h0 + flags
  rnn_init<<<dim3((HBUF_U64 + 16 + 255) / 256), dim3(256), 0, stream>>>(
      (unsigned long long*)d_ws);
  rnn_main<<<dim3(GROUPS * MEMBERS), dim3(THREADS), 0, stream>>>(
      x, W, b, out, hbuf, flags);
}